// Round 9
// baseline (47.241 us; speedup 1.0000x reference)
//
#include <hip/hip_runtime.h>
#include <math.h>

#define D 2048
#define NROWS 8192      // B*T = 4*2048
#define NBUF 512
#define RC 128          // row chunks in k1 (partial = RC*D*4 = 1 MB in ws)
#define ROWS_PER_CHUNK 64
#define WVB 4           // waves per k4 block (1 row per wave)

__device__ __forceinline__ float rcpf(float v) { return __builtin_amdgcn_rcpf(v); }

// tanh-GELU via sigmoid identity, division-free: x*sigmoid(2*a*(x+0.044715x^3))
__device__ __forceinline__ float gelu_f(float v) {
    float u = v * (1.0f + 0.044715f * v * v);
    float t = -1.5957691216057308f * u;            // -2*sqrt(2/pi)*u
    return v * rcpf(1.0f + __expf(t));
}

// ---- k1: partial column sums of gelu(x). grid (2, RC), block 256.
__global__ __launch_bounds__(256) void k1_colsum(const float* __restrict__ x,
                                                 float* __restrict__ partial) {
    const int cg = blockIdx.x * 256 + threadIdx.x;   // float4 column group [0,512)
    const int r0 = blockIdx.y * ROWS_PER_CHUNK;
    const float4* x4 = (const float4*)x;
    float ax = 0.f, ay = 0.f, az = 0.f, aw = 0.f;
    #pragma unroll 4
    for (int r = 0; r < ROWS_PER_CHUNK; ++r) {
        float4 v = x4[(size_t)(r0 + r) * (D / 4) + cg];
        ax += gelu_f(v.x); ay += gelu_f(v.y); az += gelu_f(v.z); aw += gelu_f(v.w);
    }
    float4 o; o.x = ax; o.y = ay; o.z = az; o.w = aw;
    ((float4*)partial)[(size_t)blockIdx.y * (D / 4) + cg] = o;
}

// ---- k1b: reduce RC partials -> ysum[D]. grid 64, block 256 (32 cols x 8 k-slices).
__global__ __launch_bounds__(256) void k1b_reduce(const float* __restrict__ partial,
                                                  float* __restrict__ ysum) {
    const int tid = threadIdx.x;
    const int col   = blockIdx.x * 32 + (tid & 31);
    const int slice = tid >> 5;
    const int k0 = slice * (RC / 8);
    float s = 0.f;
    #pragma unroll 16
    for (int k = 0; k < RC / 8; ++k) s += partial[(size_t)(k0 + k) * D + col];
    __shared__ float red[256];
    red[tid] = s;
    __syncthreads();
    if (tid < 32) {
        float t = red[tid];
        #pragma unroll
        for (int j = 1; j < 8; ++j) t += red[j * 32 + tid];
        ysum[blockIdx.x * 32 + tid] = t;
    }
}

// ---- k2: per-buf-row dot + ||buf_b||^2, plus ||xbuf_b||^2 and ||xbuf_b - xg||^2.
//      Block NBUF computes ||ysum||^2. grid NBUF+1.
__global__ __launch_bounds__(256) void k2_sims(const float* __restrict__ buf,
                                               const float* __restrict__ xbuf,
                                               const float* __restrict__ xglobal,
                                               const float* __restrict__ ysum,
                                               float* __restrict__ dotv,
                                               float* __restrict__ bn2,
                                               float* __restrict__ xn2,
                                               float* __restrict__ nd2,
                                               float* __restrict__ yn2) {
    const int tid = threadIdx.x;
    const int b = blockIdx.x;
    float dacc = 0.f, nacc = 0.f, xacc = 0.f, ndacc = 0.f;
    const float4* y4 = (const float4*)ysum;
    if (b < NBUF) {
        const float4* b4 = (const float4*)(buf + (size_t)b * D);
        const float4* s4 = (const float4*)(xbuf + (size_t)b * D);
        const float4* g4 = (const float4*)xglobal;
        #pragma unroll
        for (int c = tid; c < D / 4; c += 256) {
            float4 bv = b4[c]; float4 yv = y4[c];
            float4 sv = s4[c]; float4 gv = g4[c];
            dacc += bv.x * yv.x + bv.y * yv.y + bv.z * yv.z + bv.w * yv.w;
            nacc += bv.x * bv.x + bv.y * bv.y + bv.z * bv.z + bv.w * bv.w;
            xacc += sv.x * sv.x + sv.y * sv.y + sv.z * sv.z + sv.w * sv.w;
            float nx = sv.x - gv.x, ny = sv.y - gv.y, nz = sv.z - gv.z, nw = sv.w - gv.w;
            ndacc += nx * nx + ny * ny + nz * nz + nw * nw;
        }
    } else {
        #pragma unroll
        for (int c = tid; c < D / 4; c += 256) {
            float4 yv = y4[c];
            dacc += yv.x * yv.x + yv.y * yv.y + yv.z * yv.z + yv.w * yv.w;
        }
    }
    #pragma unroll
    for (int off = 32; off; off >>= 1) {
        dacc  += __shfl_down(dacc,  off, 64);
        nacc  += __shfl_down(nacc,  off, 64);
        xacc  += __shfl_down(xacc,  off, 64);
        ndacc += __shfl_down(ndacc, off, 64);
    }
    __shared__ float sa[4], sb[4], sc[4], sd[4];
    const int lane = tid & 63, w = tid >> 6;
    if (lane == 0) { sa[w] = dacc; sb[w] = nacc; sc[w] = xacc; sd[w] = ndacc; }
    __syncthreads();
    if (tid == 0) {
        float dt = sa[0] + sa[1] + sa[2] + sa[3];
        float nt = sb[0] + sb[1] + sb[2] + sb[3];
        float xt = sc[0] + sc[1] + sc[2] + sc[3];
        float nd = sd[0] + sd[1] + sd[2] + sd[3];
        if (b < NBUF) { dotv[b] = dt; bn2[b] = nt; xn2[b] = xt; nd2[b] = nd; }
        else yn2[0] = dt;
    }
}

// ---- k4: barrier-free wave-per-row. Each wave (64 lanes x 32 elems) owns one
//      row end-to-end: per-wave selection via shfl_xor butterfly (no LDS, no
//      __syncthreads anywhere), x row held in 32 VGPRs (single HBM/L3 read),
//      f = s-g held in 32 VGPRs (s,g read exactly once per wave). grid NROWS/4.
__global__ __launch_bounds__(256) void k4_out(const float* __restrict__ x,
                                              const float* __restrict__ xbuf,
                                              const float* __restrict__ xglobal,
                                              const float* __restrict__ dotv,
                                              const float* __restrict__ bn2,
                                              const float* __restrict__ xn2,
                                              const float* __restrict__ nd2,
                                              const float* __restrict__ yn2,
                                              const int* __restrict__ mask,
                                              const float* __restrict__ inj,
                                              const float* __restrict__ log_inject,
                                              float* __restrict__ out) {
    const int tid = threadIdx.x;
    const int lane = tid & 63;
    const int wv = tid >> 6;
    const size_t row = (size_t)blockIdx.x * WVB + wv;

    // ---------- issue x-row loads first (latency hides under selection) ----------
    const float4* xr = (const float4*)(x + row * D);
    float4 xv[8];
    #pragma unroll
    for (int c = 0; c < 8; ++c) xv[c] = xr[c * 64 + lane];

    // ---------- per-wave selection (shfl-only; deterministic; no fences needed:
    //            k2's outputs are visible at the kernel boundary) ----------
    float bv = -INFINITY; int bi = 1 << 30;
    {
        const float rnm = rcpf(fmaxf(sqrtf(yn2[0]) * (1.0f / 8192.0f), 1e-12f));
        #pragma unroll
        for (int k = 0; k < NBUF / 64; ++k) {
            const int i = k * 64 + lane;
            float nb = fmaxf(sqrtf(bn2[i]), 1e-12f);
            float sim = (dotv[i] * (1.0f / 8192.0f)) * rnm * rcpf(nb);
            if (!mask[i]) sim = -1.0f;
            if (sim > bv) { bv = sim; bi = i; }   // per-lane i increasing: > keeps lowest
        }
        #pragma unroll
        for (int off = 32; off; off >>= 1) {
            float ov = __shfl_xor(bv, off, 64);
            int   oi = __shfl_xor(bi, off, 64);
            if (ov > bv || (ov == bv && oi < bi)) { bv = ov; bi = oi; }
        }
    }
    const int idx = bi;                            // uniform across wave
    float ib = fminf(fmaxf(__expf(log_inject[0]), 0.001f), 2.0f);
    float inear = inj[idx];
    const float inj_level = (bv > 0.85f) ? ((inear < 1e-6f) ? ib : inear * 2.0f) : inear;
    const float rnudge  = rcpf(fmaxf(sqrtf(nd2[idx]), 1e-6f));
    const float rstored = rcpf(fmaxf(sqrtf(xn2[idx]), 1e-12f));

    // ---------- single pass over s,g: dot accumulate + f = s-g into regs ----------
    const float4* sr = (const float4*)(xbuf + (size_t)idx * D);
    const float4* gr = (const float4*)xglobal;
    float4 fv[8];
    float ds = 0.f, dxx = 0.f;
    #pragma unroll
    for (int c = 0; c < 8; ++c) {
        float4 sv = sr[c * 64 + lane];
        float4 gv = gr[c * 64 + lane];
        float4 v = xv[c];
        ds  += v.x * sv.x + v.y * sv.y + v.z * sv.z + v.w * sv.w;
        dxx += v.x * v.x + v.y * v.y + v.z * v.z + v.w * v.w;
        fv[c].x = sv.x - gv.x; fv[c].y = sv.y - gv.y;
        fv[c].z = sv.z - gv.z; fv[c].w = sv.w - gv.w;
    }
    #pragma unroll
    for (int off = 32; off; off >>= 1) {
        ds  += __shfl_xor(ds,  off, 64);
        dxx += __shfl_xor(dxx, off, 64);
    }
    const float rx = rcpf(fmaxf(sqrtf(dxx), 1e-12f));
    const float ts = fminf(fmaxf(ds * rx * rstored, 0.0f), 1.0f);   // tok_sim
    const float cc = (inj_level < 1e-6f) ? 0.0f : inj_level * ts * rnudge;

    // ---------- gelu + store (no barrier was ever needed) ----------
    float4* orow = (float4*)(out + row * D);
    #pragma unroll
    for (int c = 0; c < 8; ++c) {
        float4 v = xv[c], f = fv[c], o;
        o.x = gelu_f(v.x + cc * f.x); o.y = gelu_f(v.y + cc * f.y);
        o.z = gelu_f(v.z + cc * f.z); o.w = gelu_f(v.w + cc * f.w);
        orow[c * 64 + lane] = o;
    }
}

extern "C" void kernel_launch(void* const* d_in, const int* in_sizes, int n_in,
                              void* d_out, int out_size, void* d_ws, size_t ws_size,
                              hipStream_t stream) {
    const float* x          = (const float*)d_in[0];
    const float* log_inject = (const float*)d_in[1];
    const float* buf        = (const float*)d_in[2];
    const float* xbuf       = (const float*)d_in[3];
    const float* inj        = (const float*)d_in[4];
    const float* xglobal    = (const float*)d_in[5];
    const int*   mask       = (const int*)d_in[6];
    float* out = (float*)d_out;
    float* ws  = (float*)d_ws;

    float* ysum    = ws;            // [2048]
    float* dotv    = ws + 2048;     // [512]
    float* bn2     = ws + 2560;     // [512]
    float* xn2     = ws + 3072;     // [512]
    float* nd2     = ws + 3584;     // [512]
    float* yn2     = ws + 4088;     // [1]
    float* partial = ws + 4096;     // [RC * D] = 1 MB

    k1_colsum<<<dim3(2, RC), 256, 0, stream>>>(x, partial);
    k1b_reduce<<<64, 256, 0, stream>>>(partial, ysum);
    k2_sims<<<NBUF + 1, 256, 0, stream>>>(buf, xbuf, xglobal, ysum,
                                          dotv, bn2, xn2, nd2, yn2);
    k4_out<<<NROWS / WVB, 256, 0, stream>>>(x, xbuf, xglobal, dotv, bn2,
                                            xn2, nd2, yn2, mask, inj,
                                            log_inject, out);
}

// Round 10
// 43.529 us; speedup vs baseline: 1.0853x; 1.0853x over previous
//
#include <hip/hip_runtime.h>
#include <math.h>

#define D 2048
#define NROWS 8192      // B*T = 4*2048
#define NBUF 512
#define RC 256          // row chunks in k1 (partial = RC*D*4 = 2 MB in ws)
#define ROWS_PER_CHUNK 32
#define K4_ROWS 4       // rows per k4 block

__device__ __forceinline__ float rcpf(float v) { return __builtin_amdgcn_rcpf(v); }

// tanh-GELU via sigmoid identity, division-free: x*sigmoid(2*a*(x+0.044715x^3))
__device__ __forceinline__ float gelu_f(float v) {
    float u = v * (1.0f + 0.044715f * v * v);
    float t = -1.5957691216057308f * u;            // -2*sqrt(2/pi)*u
    return v * rcpf(1.0f + __expf(t));
}

__device__ __forceinline__ float dot8(float4 p0, float4 p1, float4 q0, float4 q1) {
    return p0.x * q0.x + p0.y * q0.y + p0.z * q0.z + p0.w * q0.w
         + p1.x * q1.x + p1.y * q1.y + p1.z * q1.z + p1.w * q1.w;
}

// ---- k1: partial column sums of gelu(x). grid (2, RC), block 256.
//      512 blocks = 2/CU = 8 waves/CU; unroll 8 -> ~64 KB loads in flight per CU
//      (Little's law needs ~22 KB for 24.6 GB/s/CU at ~900ns HBM latency).
__global__ __launch_bounds__(256) void k1_colsum(const float* __restrict__ x,
                                                 float* __restrict__ partial) {
    const int cg = blockIdx.x * 256 + threadIdx.x;   // float4 column group [0,512)
    const int r0 = blockIdx.y * ROWS_PER_CHUNK;
    const float4* x4 = (const float4*)x;
    float ax = 0.f, ay = 0.f, az = 0.f, aw = 0.f;
    #pragma unroll 8
    for (int r = 0; r < ROWS_PER_CHUNK; ++r) {
        float4 v = x4[(size_t)(r0 + r) * (D / 4) + cg];
        ax += gelu_f(v.x); ay += gelu_f(v.y); az += gelu_f(v.z); aw += gelu_f(v.w);
    }
    float4 o; o.x = ax; o.y = ay; o.z = az; o.w = aw;
    ((float4*)partial)[(size_t)blockIdx.y * (D / 4) + cg] = o;
}

// ---- k1b: reduce RC partials -> ysum[D]. grid 64, block 256 (32 cols x 8 k-slices).
__global__ __launch_bounds__(256) void k1b_reduce(const float* __restrict__ partial,
                                                  float* __restrict__ ysum) {
    const int tid = threadIdx.x;
    const int col   = blockIdx.x * 32 + (tid & 31);
    const int slice = tid >> 5;
    const int k0 = slice * (RC / 8);
    float s = 0.f;
    #pragma unroll 8
    for (int k = 0; k < RC / 8; ++k) s += partial[(size_t)(k0 + k) * D + col];
    __shared__ float red[256];
    red[tid] = s;
    __syncthreads();
    if (tid < 32) {
        float t = red[tid];
        #pragma unroll
        for (int j = 1; j < 8; ++j) t += red[j * 32 + tid];
        ysum[blockIdx.x * 32 + tid] = t;
    }
}

// ---- k2: per-buf-row dot + ||buf_b||^2, plus ||xbuf_b||^2 and ||xbuf_b - xg||^2.
//      Block NBUF computes ||ysum||^2. grid NBUF+1.
__global__ __launch_bounds__(256) void k2_sims(const float* __restrict__ buf,
                                               const float* __restrict__ xbuf,
                                               const float* __restrict__ xglobal,
                                               const float* __restrict__ ysum,
                                               float* __restrict__ dotv,
                                               float* __restrict__ bn2,
                                               float* __restrict__ xn2,
                                               float* __restrict__ nd2,
                                               float* __restrict__ yn2) {
    const int tid = threadIdx.x;
    const int b = blockIdx.x;
    float dacc = 0.f, nacc = 0.f, xacc = 0.f, ndacc = 0.f;
    const float4* y4 = (const float4*)ysum;
    if (b < NBUF) {
        const float4* b4 = (const float4*)(buf + (size_t)b * D);
        const float4* s4 = (const float4*)(xbuf + (size_t)b * D);
        const float4* g4 = (const float4*)xglobal;
        #pragma unroll
        for (int c = tid; c < D / 4; c += 256) {
            float4 bv = b4[c]; float4 yv = y4[c];
            float4 sv = s4[c]; float4 gv = g4[c];
            dacc += bv.x * yv.x + bv.y * yv.y + bv.z * yv.z + bv.w * yv.w;
            nacc += bv.x * bv.x + bv.y * bv.y + bv.z * bv.z + bv.w * bv.w;
            xacc += sv.x * sv.x + sv.y * sv.y + sv.z * sv.z + sv.w * sv.w;
            float nx = sv.x - gv.x, ny = sv.y - gv.y, nz = sv.z - gv.z, nw = sv.w - gv.w;
            ndacc += nx * nx + ny * ny + nz * nz + nw * nw;
        }
    } else {
        #pragma unroll
        for (int c = tid; c < D / 4; c += 256) {
            float4 yv = y4[c];
            dacc += yv.x * yv.x + yv.y * yv.y + yv.z * yv.z + yv.w * yv.w;
        }
    }
    #pragma unroll
    for (int off = 32; off; off >>= 1) {
        dacc  += __shfl_down(dacc,  off, 64);
        nacc  += __shfl_down(nacc,  off, 64);
        xacc  += __shfl_down(xacc,  off, 64);
        ndacc += __shfl_down(ndacc, off, 64);
    }
    __shared__ float sa[4], sb[4], sc[4], sd[4];
    const int lane = tid & 63, w = tid >> 6;
    if (lane == 0) { sa[w] = dacc; sb[w] = nacc; sc[w] = xacc; sd[w] = ndacc; }
    __syncthreads();
    if (tid == 0) {
        float dt = sa[0] + sa[1] + sa[2] + sa[3];
        float nt = sb[0] + sb[1] + sb[2] + sb[3];
        float xt = sc[0] + sc[1] + sc[2] + sc[3];
        float nd = sd[0] + sd[1] + sd[2] + sd[3];
        if (b < NBUF) { dotv[b] = dt; bn2[b] = nt; xn2[b] = xt; nd2[b] = nd; }
        else yn2[0] = dt;
    }
}

// ---- k4: 4 rows/block, x held in registers (R6 structure, proven 44.0 — unchanged).
__global__ __launch_bounds__(256) void k4_out(const float* __restrict__ x,
                                              const float* __restrict__ xbuf,
                                              const float* __restrict__ xglobal,
                                              const float* __restrict__ dotv,
                                              const float* __restrict__ bn2,
                                              const float* __restrict__ xn2,
                                              const float* __restrict__ nd2,
                                              const float* __restrict__ yn2,
                                              const int* __restrict__ mask,
                                              const float* __restrict__ inj,
                                              const float* __restrict__ log_inject,
                                              float* __restrict__ out) {
    const int tid = threadIdx.x;
    const int lane = tid & 63, w = tid >> 6;
    const size_t row0 = (size_t)blockIdx.x * K4_ROWS;

    // ---------- issue x loads early: 4 rows x 2 float4/thread ----------
    const float4* xr0 = (const float4*)(x + (row0 + 0) * D);
    const float4* xr1 = (const float4*)(x + (row0 + 1) * D);
    const float4* xr2 = (const float4*)(x + (row0 + 2) * D);
    const float4* xr3 = (const float4*)(x + (row0 + 3) * D);
    const float4 a0 = xr0[tid], a1 = xr0[tid + 256];
    const float4 b0 = xr1[tid], b1 = xr1[tid + 256];
    const float4 c0 = xr2[tid], c1 = xr2[tid + 256];
    const float4 d0 = xr3[tid], d1 = xr3[tid + 256];

    // ---------- phase 0: selection (identical in every block) ----------
    __shared__ float sv[4]; __shared__ int si[4];
    __shared__ int s_idx;
    __shared__ float s_lvl, s_rnudge, s_rstored;
    {
        const float rnm = rcpf(fmaxf(sqrtf(yn2[0]) * (1.0f / 8192.0f), 1e-12f));
        float bv; int bi;
        {
            const int i = tid;
            float nb = fmaxf(sqrtf(bn2[i]), 1e-12f);
            float sim = (dotv[i] * (1.0f / 8192.0f)) * rnm * rcpf(nb);
            if (!mask[i]) sim = -1.0f;
            bv = sim; bi = i;
        }
        {
            const int i = tid + 256;
            float nb = fmaxf(sqrtf(bn2[i]), 1e-12f);
            float sim = (dotv[i] * (1.0f / 8192.0f)) * rnm * rcpf(nb);
            if (!mask[i]) sim = -1.0f;
            if (sim > bv) { bv = sim; bi = i; }           // tie keeps lower index
        }
        #pragma unroll
        for (int off = 32; off; off >>= 1) {
            float ov = __shfl_down(bv, off, 64);
            int   oi = __shfl_down(bi, off, 64);
            if (ov > bv || (ov == bv && oi < bi)) { bv = ov; bi = oi; }
        }
        if (lane == 0) { sv[w] = bv; si[w] = bi; }
        __syncthreads();
        if (tid == 0) {
            float fv = sv[0]; int fi = si[0];
            #pragma unroll
            for (int j = 1; j < 4; ++j) {
                if (sv[j] > fv || (sv[j] == fv && si[j] < fi)) { fv = sv[j]; fi = si[j]; }
            }
            float ib = fminf(fmaxf(__expf(log_inject[0]), 0.001f), 2.0f);
            float inear = inj[fi];
            s_lvl = (fv > 0.85f) ? ((inear < 1e-6f) ? ib : inear * 2.0f) : inear;
            s_idx = fi;
            s_rnudge  = rcpf(fmaxf(sqrtf(nd2[fi]), 1e-6f));
            s_rstored = rcpf(fmaxf(sqrtf(xn2[fi]), 1e-12f));
        }
        __syncthreads();
    }
    const int   idx       = s_idx;
    const float inj_level = s_lvl;
    const float rnudge    = s_rnudge;
    const float rstored   = s_rstored;

    // ---------- phase 1: stored/global rows (reused by all 4 rows) ----------
    const float4* sr = (const float4*)(xbuf + (size_t)idx * D);
    const float4* gr = (const float4*)xglobal;
    const float4 s0 = sr[tid], s1 = sr[tid + 256];
    const float4 g0 = gr[tid], g1 = gr[tid + 256];

    float d0s = dot8(a0, a1, s0, s1), d0x = dot8(a0, a1, a0, a1);
    float d1s = dot8(b0, b1, s0, s1), d1x = dot8(b0, b1, b0, b1);
    float d2s = dot8(c0, c1, s0, s1), d2x = dot8(c0, c1, c0, c1);
    float d3s = dot8(d0, d1, s0, s1), d3x = dot8(d0, d1, d0, d1);

    #pragma unroll
    for (int off = 32; off; off >>= 1) {
        d0s += __shfl_down(d0s, off, 64);
        d0x += __shfl_down(d0x, off, 64);
        d1s += __shfl_down(d1s, off, 64);
        d1x += __shfl_down(d1x, off, 64);
        d2s += __shfl_down(d2s, off, 64);
        d2x += __shfl_down(d2x, off, 64);
        d3s += __shfl_down(d3s, off, 64);
        d3x += __shfl_down(d3x, off, 64);
    }
    __shared__ float red8[8][4];
    if (lane == 0) {
        red8[0][w] = d0s; red8[1][w] = d0x;
        red8[2][w] = d1s; red8[3][w] = d1x;
        red8[4][w] = d2s; red8[5][w] = d2x;
        red8[6][w] = d3s; red8[7][w] = d3x;
    }
    __syncthreads();
    __shared__ float s_c[4];
    if (tid < 4) {
        const int r = tid;
        float dt = red8[2 * r][0] + red8[2 * r][1] + red8[2 * r][2] + red8[2 * r][3];
        float nt = red8[2 * r + 1][0] + red8[2 * r + 1][1] + red8[2 * r + 1][2] + red8[2 * r + 1][3];
        float rx = rcpf(fmaxf(sqrtf(nt), 1e-12f));
        float ts = fminf(fmaxf(dt * rx * rstored, 0.0f), 1.0f);  // tok_sim
        s_c[r] = (inj_level < 1e-6f) ? 0.0f : inj_level * ts * rnudge;
    }
    __syncthreads();

    // diffs computed once, reused across 4 rows
    float4 f0, f1;
    f0.x = s0.x - g0.x; f0.y = s0.y - g0.y; f0.z = s0.z - g0.z; f0.w = s0.w - g0.w;
    f1.x = s1.x - g1.x; f1.y = s1.y - g1.y; f1.z = s1.z - g1.z; f1.w = s1.w - g1.w;

    {
        const float c = s_c[0];
        float4 o0, o1;
        o0.x = gelu_f(a0.x + c * f0.x); o0.y = gelu_f(a0.y + c * f0.y);
        o0.z = gelu_f(a0.z + c * f0.z); o0.w = gelu_f(a0.w + c * f0.w);
        o1.x = gelu_f(a1.x + c * f1.x); o1.y = gelu_f(a1.y + c * f1.y);
        o1.z = gelu_f(a1.z + c * f1.z); o1.w = gelu_f(a1.w + c * f1.w);
        float4* orow = (float4*)(out + (row0 + 0) * D);
        orow[tid] = o0; orow[tid + 256] = o1;
    }
    {
        const float c = s_c[1];
        float4 o0, o1;
        o0.x = gelu_f(b0.x + c * f0.x); o0.y = gelu_f(b0.y + c * f0.y);
        o0.z = gelu_f(b0.z + c * f0.z); o0.w = gelu_f(b0.w + c * f0.w);
        o1.x = gelu_f(b1.x + c * f1.x); o1.y = gelu_f(b1.y + c * f1.y);
        o1.z = gelu_f(b1.z + c * f1.z); o1.w = gelu_f(b1.w + c * f1.w);
        float4* orow = (float4*)(out + (row0 + 1) * D);
        orow[tid] = o0; orow[tid + 256] = o1;
    }
    {
        const float c = s_c[2];
        float4 o0, o1;
        o0.x = gelu_f(c0.x + c * f0.x); o0.y = gelu_f(c0.y + c * f0.y);
        o0.z = gelu_f(c0.z + c * f0.z); o0.w = gelu_f(c0.w + c * f0.w);
        o1.x = gelu_f(c1.x + c * f1.x); o1.y = gelu_f(c1.y + c * f1.y);
        o1.z = gelu_f(c1.z + c * f1.z); o1.w = gelu_f(c1.w + c * f1.w);
        float4* orow = (float4*)(out + (row0 + 2) * D);
        orow[tid] = o0; orow[tid + 256] = o1;
    }
    {
        const float c = s_c[3];
        float4 o0, o1;
        o0.x = gelu_f(d0.x + c * f0.x); o0.y = gelu_f(d0.y + c * f0.y);
        o0.z = gelu_f(d0.z + c * f0.z); o0.w = gelu_f(d0.w + c * f0.w);
        o1.x = gelu_f(d1.x + c * f1.x); o1.y = gelu_f(d1.y + c * f1.y);
        o1.z = gelu_f(d1.z + c * f1.z); o1.w = gelu_f(d1.w + c * f1.w);
        float4* orow = (float4*)(out + (row0 + 3) * D);
        orow[tid] = o0; orow[tid + 256] = o1;
    }
}

extern "C" void kernel_launch(void* const* d_in, const int* in_sizes, int n_in,
                              void* d_out, int out_size, void* d_ws, size_t ws_size,
                              hipStream_t stream) {
    const float* x          = (const float*)d_in[0];
    const float* log_inject = (const float*)d_in[1];
    const float* buf        = (const float*)d_in[2];
    const float* xbuf       = (const float*)d_in[3];
    const float* inj        = (const float*)d_in[4];
    const float* xglobal    = (const float*)d_in[5];
    const int*   mask       = (const int*)d_in[6];
    float* out = (float*)d_out;
    float* ws  = (float*)d_ws;

    float* ysum    = ws;            // [2048]
    float* dotv    = ws + 2048;     // [512]
    float* bn2     = ws + 2560;     // [512]
    float* xn2     = ws + 3072;     // [512]
    float* nd2     = ws + 3584;     // [512]
    float* yn2     = ws + 4088;     // [1]
    float* partial = ws + 4096;     // [RC * D] = 2 MB

    k1_colsum<<<dim3(2, RC), 256, 0, stream>>>(x, partial);
    k1b_reduce<<<64, 256, 0, stream>>>(partial, ysum);
    k2_sims<<<NBUF + 1, 256, 0, stream>>>(buf, xbuf, xglobal, ysum,
                                          dotv, bn2, xn2, nd2, yn2);
    k4_out<<<NROWS / K4_ROWS, 256, 0, stream>>>(x, xbuf, xglobal, dotv, bn2,
                                                xn2, nd2, yn2, mask, inj,
                                                log_inject, out);
}